// Round 12
// baseline (122.437 us; speedup 1.0000x reference)
//
#include <hip/hip_runtime.h>

// ChebGraphConv as ONE flat GEMM (K=192) over contiguous rows r = bt*1024+n:
//   out[r][o] = sum_{k,c} (d_k[n(r)] * x[r][c]) * Theta[k][c][o] + sum_k bias[k][o]
// R12 = R10 + FULL-LINE STORES. R10/R11 A/B showed NT stores beat normal
// (4.4 vs 3.3 TB/s effective) but paid +37% write bytes from 64B partial-line
// segments. Fix: LDS pair-exchange epilogue -- waves write acc to a per-pair
// 4KB outb (XOR-swizzled), read back row-dense after the next barrier, so
// each NT store is a contiguous 1KB (8 full 128B lines): fast path AND
// minimal bytes. 3 x-buffers + 2 out-buffers = 80KB = 2 blocks/CU exactly.
// vmcnt N computed iteration-robustly (only later-iter ops counted younger).
// B=32,T=24,N=1024 -> 786432 rows. C_IN=C_OUT=64, K_cheb=3.

#define NNODES 1024
#define TILE_ROWS 64
#define NT 8
#define ROWS_PER_BLOCK (TILE_ROWS * NT)         // 512
#define NBLOCKS (786432 / ROWS_PER_BLOCK)       // 1536

// ws layout
#define WS_W  0                  // 24 frags * 64 lanes * 16B = 24 KB (bf16)
#define WS_BS (24 * 1024)        // 64 * f32 summed bias
#define WS_DV (24 * 1024 + 256)  // 1024 * f32x4 {d0,d1,d2,0}

typedef __attribute__((ext_vector_type(8))) short short8;  // 8 x bf16 MFMA frag
typedef __attribute__((ext_vector_type(4))) float f32x4;   // MFMA C/D frag
typedef __attribute__((ext_vector_type(4))) int   i32x4;

// round-to-nearest-even f32 -> bf16 bits (prep kernel only)
__device__ __forceinline__ unsigned short f2bf(float f) {
    union { float f; unsigned u; } v; v.f = f;
    unsigned r = v.u + 0x7FFFu + ((v.u >> 16) & 1u);
    return (unsigned short)(r >> 16);
}

// pack 2 f32 -> 2 bf16 in one VALU op
__device__ __forceinline__ int cvt_pk_bf16(float lo, float hi) {
    int r;
    asm("v_cvt_pk_bf16_f32 %0, %1, %2" : "=v"(r) : "v"(lo), "v"(hi));
    return r;
}

// dense global->LDS: wave-uniform LDS base, lane l lands at base + l*16
__device__ __forceinline__ void gload_lds16(const void* g, void* l) {
    __builtin_amdgcn_global_load_lds(
        (const __attribute__((address_space(1))) void*)g,
        (__attribute__((address_space(3))) void*)l,
        16, 0, 0);
}

__global__ void cheb_prep(const float* __restrict__ Tks,
                          const float* __restrict__ Theta,
                          const float* __restrict__ bias,
                          unsigned char* __restrict__ ws) {
    const int b = blockIdx.x;
    const int l = threadIdx.x;   // 64 threads
    if (b < 24) {
        // frag f = (kc*2+h)*4 + nb ; lane l holds W^T row o = nb*16+(l&15),
        // k-slice c = h*32 + (l>>4)*8 + j  (A-operand layout, 16x16x32)
        const int kc = b >> 3, h = (b >> 2) & 1, nb = b & 3;
        const int o  = nb * 16 + (l & 15);
        const int cb = h * 32 + (l >> 4) * 8;
        unsigned short* dst = (unsigned short*)(ws + WS_W) + ((size_t)b * 64 + l) * 8;
        #pragma unroll
        for (int j = 0; j < 8; ++j)
            dst[j] = f2bf(Theta[kc * 4096 + (cb + j) * 64 + o]);
    } else if (b < 40) {
        const int n = (b - 24) * 64 + l;
        const size_t dg = (size_t)n * (NNODES + 1);
        f32x4 v;
        v[0] = Tks[dg];
        v[1] = Tks[(size_t)NNODES * NNODES + dg];
        v[2] = Tks[(size_t)2 * NNODES * NNODES + dg];
        v[3] = 0.0f;
        *((f32x4*)(ws + WS_DV) + n) = v;
    } else {
        float* bs = (float*)(ws + WS_BS);
        bs[l] = bias[l] + bias[64 + l] + bias[128 + l];
    }
}

__global__ __launch_bounds__(512, 4) void cheb_main(
    const float* __restrict__ x,          // [786432 * 64]
    const unsigned char* __restrict__ ws,
    float* __restrict__ out)              // [786432 * 64]
{
    __shared__ float xs[3][TILE_ROWS * 64];   // 48 KB swizzled x tiles
    __shared__ float outb[2][4][16 * 64];     // 32 KB: 2 bufs x 4 pairs x 4KB

    const int tid  = threadIdx.x;
    const int wave = tid >> 6;    // 0..7
    const int lane = tid & 63;
    const int lrow = lane & 15;
    const int lgrp = lane >> 4;
    const int wr   = wave >> 1;   // pair id 0..3 (rows wr*16..wr*16+15)
    const int q    = wave & 1;    // o-half
    const size_t rowbase = (size_t)blockIdx.x * ROWS_PER_BLOCK;

    const unsigned short* wimg  = (const unsigned short*)(ws + WS_W);
    const float*          bsum  = (const float*)(ws + WS_BS);
    const f32x4*          dvec4 = (const f32x4*)(ws + WS_DV);

    // ---- prologue: all vmem here is OLDER than stage(0) ----
    short8 wf[3][2][2];                   // 12 W-frags for this o-half (48 VGPR)
    #pragma unroll
    for (int kc = 0; kc < 3; ++kc)
        #pragma unroll
        for (int h = 0; h < 2; ++h)
            #pragma unroll
            for (int nb = 0; nb < 2; ++nb)
                wf[kc][h][nb] = *(const short8*)(
                    wimg + ((size_t)(((kc * 2 + h) * 4 + q * 2 + nb) * 64 + lane)) * 8);

    f32x4 bs4[2];
    #pragma unroll
    for (int nb = 0; nb < 2; ++nb)
        bs4[nb] = *(const f32x4*)(bsum + q * 32 + nb * 16 + lgrp * 4);

    // per-iter diag scales in registers (24 VGPR): node = rowbase+T*64+wr*16+lrow
    float d0[NT], d1[NT], d2[NT];
    #pragma unroll
    for (int t = 0; t < NT; ++t) {
        const f32x4 dv = dvec4[(rowbase + t * TILE_ROWS + wr * 16 + lrow) & (NNODES - 1)];
        d0[t] = dv[0]; d1[t] = dv[1]; d2[t] = dv[2];
    }

    // ---- STAGE tile T: 16 x 1KB chunks; wave stages chunks 2w,2w+1 ----
#define STAGE(T) do { if ((T) < NT) {                                         \
        _Pragma("unroll")                                                     \
        for (int s = 0; s < 2; ++s) {                                         \
            const int u_ = wave * 2 + s;                                      \
            const int R_ = u_ * 4 + lgrp;                                     \
            const int c_ = (lrow * 16) ^ ((R_ & 7) << 4);                     \
            const char* g_ = (const char*)x +                                 \
                (((rowbase + (size_t)(T) * TILE_ROWS + R_) << 8) + c_);       \
            gload_lds16(g_, (char*)&xs[(T) % 3][0] + u_ * 1024);              \
        } } } while (0)

#define WAITB(N) do {                                                         \
        asm volatile("s_waitcnt vmcnt(" #N ") lgkmcnt(0)" ::: "memory");      \
        __builtin_amdgcn_sched_barrier(0);                                    \
        __builtin_amdgcn_s_barrier();                                         \
        __builtin_amdgcn_sched_barrier(0);                                    \
    } while (0)

    // read back tile T's out from outb (pair-exchanged) -> dense 1KB NT stores
#define EPILOG(T) do { if ((T) >= 0) {                                        \
        _Pragma("unroll")                                                     \
        for (int r = 0; r < 2; ++r) {                                         \
            const int rl = q * 8 + r * 4 + lgrp;                              \
            const int byt = (lrow * 16) ^ ((rl & 7) << 4);                    \
            const f32x4 v = *(const f32x4*)(                                  \
                (const char*)&outb[(T) & 1][wr][0] + rl * 256 + byt);         \
            __builtin_nontemporal_store(v, (f32x4*)((char*)(out +             \
                (rowbase + (size_t)(T) * TILE_ROWS + wr * 16 + rl) * 64)      \
                + lrow * 16));                                                \
        } } } while (0)

#define BODY(T) do {                                                          \
        const int m_ = (lrow & 7) << 4;                                       \
        const char* rowp = (const char*)&xs[(T) % 3][0]                       \
                         + (wr * 16 + lrow) * 256;                            \
        const int c00 = (lgrp * 32) ^ m_;                                     \
        const int c01 = (lgrp * 32 + 16) ^ m_;                                \
        const f32x4 x0 = *(const f32x4*)(rowp + c00);                         \
        const f32x4 x1 = *(const f32x4*)(rowp + c01);                         \
        const f32x4 x2 = *(const f32x4*)(rowp + 128 + c00);                   \
        const f32x4 x3 = *(const f32x4*)(rowp + 128 + c01);                   \
        const float dk0 = d0[T], dk1 = d1[T], dk2 = d2[T];                    \
        short8 xf[3][2];                                                      \
        _Pragma("unroll")                                                     \
        for (int kc = 0; kc < 3; ++kc) {                                      \
            const float dk = kc == 0 ? dk0 : (kc == 1 ? dk1 : dk2);           \
            i32x4 r0, r1;                                                     \
            r0[0] = cvt_pk_bf16(dk * x0[0], dk * x0[1]);                      \
            r0[1] = cvt_pk_bf16(dk * x0[2], dk * x0[3]);                      \
            r0[2] = cvt_pk_bf16(dk * x1[0], dk * x1[1]);                      \
            r0[3] = cvt_pk_bf16(dk * x1[2], dk * x1[3]);                      \
            r1[0] = cvt_pk_bf16(dk * x2[0], dk * x2[1]);                      \
            r1[1] = cvt_pk_bf16(dk * x2[2], dk * x2[3]);                      \
            r1[2] = cvt_pk_bf16(dk * x3[0], dk * x3[1]);                      \
            r1[3] = cvt_pk_bf16(dk * x3[2], dk * x3[3]);                      \
            xf[kc][0] = __builtin_bit_cast(short8, r0);                       \
            xf[kc][1] = __builtin_bit_cast(short8, r1);                       \
        }                                                                     \
        f32x4 acc[2] = {f32x4{0,0,0,0}, f32x4{0,0,0,0}};                      \
        __builtin_amdgcn_s_setprio(1);                                        \
        _Pragma("unroll")                                                     \
        for (int kc = 0; kc < 3; ++kc)                                        \
            _Pragma("unroll")                                                 \
            for (int h = 0; h < 2; ++h)                                       \
                _Pragma("unroll")                                             \
                for (int nb = 0; nb < 2; ++nb)                                \
                    acc[nb] = __builtin_amdgcn_mfma_f32_16x16x32_bf16(        \
                        wf[kc][h][nb], xf[kc][h], acc[nb], 0, 0, 0);          \
        __builtin_amdgcn_s_setprio(0);                                        \
        _Pragma("unroll")                                                     \
        for (int nb = 0; nb < 2; ++nb) {                                      \
            f32x4 o4;                                                         \
            _Pragma("unroll")                                                 \
            for (int j = 0; j < 4; ++j) o4[j] = acc[nb][j] + bs4[nb][j];      \
            const int byt = (q * 128 + nb * 64 + lgrp * 16) ^ m_;             \
            *(f32x4*)((char*)&outb[(T) & 1][wr][0] + lrow * 256 + byt) = o4;  \
        }                                                                     \
    } while (0)

    // ---- pipeline: iter T = [WAITB(N); STAGE(T+2); EPILOG(T-1); BODY(T)] ----
    // N robust: count only later-iteration vmem (2 gloads + 2 NT stores/iter)
    STAGE(0); STAGE(1);
    WAITB(0); STAGE(2);  EPILOG(-1); BODY(0);
    WAITB(0); STAGE(3);  EPILOG(0);  BODY(1);
    WAITB(2); STAGE(4);  EPILOG(1);  BODY(2);
    WAITB(4); STAGE(5);  EPILOG(2);  BODY(3);
    WAITB(4); STAGE(6);  EPILOG(3);  BODY(4);
    WAITB(4); STAGE(7);  EPILOG(4);  BODY(5);
    WAITB(4); STAGE(8);  EPILOG(5);  BODY(6);   // STAGE(8/9) compile out
    WAITB(2); STAGE(9);  EPILOG(6);  BODY(7);
    // final: drain LDS writes, barrier, flush last out tile
    asm volatile("s_waitcnt lgkmcnt(0)" ::: "memory");
    __builtin_amdgcn_s_barrier();
    EPILOG(7);

#undef STAGE
#undef WAITB
#undef EPILOG
#undef BODY
}

extern "C" void kernel_launch(void* const* d_in, const int* in_sizes, int n_in,
                              void* d_out, int out_size, void* d_ws, size_t ws_size,
                              hipStream_t stream) {
    const float* x     = (const float*)d_in[0];
    const float* Tks   = (const float*)d_in[1];
    const float* Theta = (const float*)d_in[2];
    const float* bias  = (const float*)d_in[3];
    float* out = (float*)d_out;
    unsigned char* ws = (unsigned char*)d_ws;

    hipLaunchKernelGGL(cheb_prep, dim3(41), dim3(64), 0, stream,
                       Tks, Theta, bias, ws);
    hipLaunchKernelGGL(cheb_main, dim3(NBLOCKS), dim3(512), 0, stream,
                       x, ws, out);
}